// Round 1
// baseline (102.552 us; speedup 1.0000x reference)
//
#include <hip/hip_runtime.h>
#include <hip/hip_bf16.h>

#define NL  128   // layers (n)
#define DK  256   // d_in (k)
#define DO_ 256   // d_out (o)
#define MB  1024  // batch (m)

typedef __attribute__((ext_vector_type(4))) float f32x4;
typedef __attribute__((ext_vector_type(8))) short bf16x8;
typedef __attribute__((ext_vector_type(8))) unsigned short u16x8;

static __device__ __forceinline__ unsigned short f2bf(float f) {
  __hip_bfloat16 h = __float2bfloat16(f);
  return __builtin_bit_cast(unsigned short, h);
}

// ---------------------------------------------------------------------------
// Prep: W[n][k][o] fp32  ->  Wt[n][o][k] bf16  (transpose + convert, in d_ws)
// grid (16, 128): blockIdx.x = (ktile<<2)|otile quadrants of the 256x256 slice
// ---------------------------------------------------------------------------
__global__ __launch_bounds__(256) void wt_prep(const float* __restrict__ W,
                                               unsigned short* __restrict__ Wt) {
  const int n     = blockIdx.y;
  const int ktile = (blockIdx.x >> 2) * 64;
  const int otile = (blockIdx.x & 3) * 64;
  __shared__ float tile[64][65];  // +1 pad: conflict-free column reads
  const float* Wn = W + (size_t)n * DK * DO_;
  const int t  = threadIdx.x;
  const int lr = t >> 4;         // 0..15
  const int lc = (t & 15) * 4;   // 0..60
#pragma unroll
  for (int p = 0; p < 4; ++p) {
    const int k = p * 16 + lr;
    const float4 v = *(const float4*)(Wn + (size_t)(ktile + k) * DO_ + otile + lc);
    tile[k][lc + 0] = v.x; tile[k][lc + 1] = v.y;
    tile[k][lc + 2] = v.z; tile[k][lc + 3] = v.w;
  }
  __syncthreads();
  const int o  = t >> 2;  // 0..63
  const int kq = t & 3;   // 16 k each
  u16x8 w0, w1;
#pragma unroll
  for (int j = 0; j < 8; ++j) w0[j] = f2bf(tile[kq * 16 + j][o]);
#pragma unroll
  for (int j = 0; j < 8; ++j) w1[j] = f2bf(tile[kq * 16 + 8 + j][o]);
  unsigned short* dst = Wt + ((size_t)(n * DO_ + otile + o) * DK + ktile + kq * 16);
  *(u16x8*)(dst)     = w0;
  *(u16x8*)(dst + 8) = w1;
}

// ---------------------------------------------------------------------------
// Main: per block (n, 64-row m-tile) x full 256 o.  4 waves, wave = 64m x 64o.
// A: fp32 -> bf16 reg-staged into double-buffered, XOR-swizzled LDS.
// B: 16B k-contiguous gathers straight from Wt (L2-resident).
// ---------------------------------------------------------------------------
__global__ __launch_bounds__(256, 3) void nlinear_mfma(
    const float* __restrict__ X, const unsigned short* __restrict__ Wt,
    const float* __restrict__ bias, float* __restrict__ out) {
  const int n     = blockIdx.y;
  const int mbase = blockIdx.x * 64;
  const int t     = threadIdx.x;
  const int wave  = t >> 6;      // o-wave 0..3
  const int lane  = t & 63;
  const int lrow  = lane & 15;
  const int lhi   = lane >> 4;   // 0..3

  __shared__ unsigned short Alds[2][64 * 64];  // [buf][row*64 + k], 128B rows, swizzled

  // staging map: each thread owns (row, 16-k quarter) of the 64x64 A tile
  const int srow = t >> 2;
  const int skq  = t & 3;
  const float* xsrc = X + ((size_t)(mbase + srow) * NL + n) * DK + skq * 16;

  const unsigned short* Wn = Wt + (size_t)n * DO_ * DK;

  f32x4 acc[4][4];
#pragma unroll
  for (int i = 0; i < 4; ++i)
#pragma unroll
    for (int j = 0; j < 4; ++j) acc[i][j] = (f32x4){0.f, 0.f, 0.f, 0.f};

  // prologue: stage K-step 0 into buf 0
  {
    float4 sv[4];
#pragma unroll
    for (int j = 0; j < 4; ++j) sv[j] = *(const float4*)(xsrc + j * 4);
    char* ab = (char*)Alds[0];
#pragma unroll
    for (int j = 0; j < 2; ++j) {
      u16x8 w;
      const float* p0 = (const float*)&sv[2 * j];
      const float* p1 = (const float*)&sv[2 * j + 1];
#pragma unroll
      for (int e = 0; e < 4; ++e) { w[e] = f2bf(p0[e]); w[4 + e] = f2bf(p1[e]); }
      *(u16x8*)(ab + srow * 128 + ((((skq << 1) | j) ^ (srow & 7)) << 4)) = w;
    }
  }
  __syncthreads();

#pragma unroll
  for (int kk = 0; kk < 4; ++kk) {
    const int buf = kk & 1;
    // issue next tile's global loads early; they land under this tile's compute
    float4 sv[4];
    if (kk < 3) {
#pragma unroll
      for (int j = 0; j < 4; ++j)
        sv[j] = *(const float4*)(xsrc + (kk + 1) * 64 + j * 4);
    }
    // compute from Alds[buf]
    char* ab = (char*)Alds[buf];
#pragma unroll
    for (int ks = 0; ks < 2; ++ks) {
      bf16x8 af[4];
#pragma unroll
      for (int mi = 0; mi < 4; ++mi) {
        const int row  = mi * 16 + lrow;
        const int slot = (ks * 4 + lhi) ^ (row & 7);
        af[mi] = *(const bf16x8*)(ab + row * 128 + slot * 16);
      }
#pragma unroll
      for (int oj = 0; oj < 4; ++oj) {
        const bf16x8 bfr = *(const bf16x8*)(
            Wn + (size_t)(wave * 64 + oj * 16 + lrow) * DK + kk * 64 + ks * 32 + lhi * 8);
#pragma unroll
        for (int mi = 0; mi < 4; ++mi)
          acc[mi][oj] =
              __builtin_amdgcn_mfma_f32_16x16x32_bf16(af[mi], bfr, acc[mi][oj], 0, 0, 0);
      }
    }
    if (kk < 3) {
      char* ab2 = (char*)Alds[buf ^ 1];
#pragma unroll
      for (int j = 0; j < 2; ++j) {
        u16x8 w;
        const float* p0 = (const float*)&sv[2 * j];
        const float* p1 = (const float*)&sv[2 * j + 1];
#pragma unroll
        for (int e = 0; e < 4; ++e) { w[e] = f2bf(p0[e]); w[4 + e] = f2bf(p1[e]); }
        *(u16x8*)(ab2 + srow * 128 + ((((skq << 1) | j) ^ (srow & 7)) << 4)) = w;
      }
      __syncthreads();  // one barrier per K-step (double buffer removes WAR)
    }
  }

  // epilogue: C/D layout col=lane&15, row=(lane>>4)*4+reg  [m89-verified]
  float bv[4];
#pragma unroll
  for (int oj = 0; oj < 4; ++oj) bv[oj] = bias[n * DO_ + wave * 64 + oj * 16 + lrow];
#pragma unroll
  for (int mi = 0; mi < 4; ++mi)
#pragma unroll
    for (int oj = 0; oj < 4; ++oj)
#pragma unroll
      for (int r = 0; r < 4; ++r) {
        const int row = mbase + mi * 16 + lhi * 4 + r;
        const int col = wave * 64 + oj * 16 + lrow;
        out[((size_t)row * NL + n) * DO_ + col] = acc[mi][oj][r] + bv[oj];
      }
}

// ---------------------------------------------------------------------------
// Fallback (only if ws too small for Wt): plain fp32, correct but slow.
// ---------------------------------------------------------------------------
__global__ __launch_bounds__(256) void nlinear_naive(
    const float* __restrict__ X, const float* __restrict__ W,
    const float* __restrict__ B, float* __restrict__ out) {
  const int n = blockIdx.y;
  const int m = blockIdx.x;
  const int o = threadIdx.x;
  __shared__ float xs[DK];
  xs[o] = X[((size_t)m * NL + n) * DK + o];
  __syncthreads();
  const float* Wn = W + (size_t)n * DK * DO_;
  float s = B[n * DO_ + o];
  for (int k = 0; k < DK; ++k) s = fmaf(xs[k], Wn[(size_t)k * DO_ + o], s);
  out[((size_t)m * NL + n) * DO_ + o] = s;
}

extern "C" void kernel_launch(void* const* d_in, const int* in_sizes, int n_in,
                              void* d_out, int out_size, void* d_ws, size_t ws_size,
                              hipStream_t stream) {
  const float* x = (const float*)d_in[0];
  const float* w = (const float*)d_in[1];
  const float* b = (const float*)d_in[2];
  float* out     = (float*)d_out;
  const size_t wt_bytes = (size_t)NL * DK * DO_ * sizeof(unsigned short);
  if (ws_size >= wt_bytes) {
    unsigned short* wt = (unsigned short*)d_ws;
    wt_prep<<<dim3(16, NL), 256, 0, stream>>>(w, wt);
    nlinear_mfma<<<dim3(MB / 64, NL), 256, 0, stream>>>(x, wt, b, out);
  } else {
    nlinear_naive<<<dim3(MB, NL), 256, 0, stream>>>(x, w, b, out);
  }
}